// Round 10
// baseline (164.555 us; speedup 1.0000x reference)
//
#include <hip/hip_runtime.h>

#define HID   384
#define K_PE  768      // 3*16*16
#define IMGST 150528   // 3*224*224 floats per image
#define NCOLS 75264    // 196*384
#define XPHALF 9633792 // ushorts per input in Xp: 196*64*768

typedef unsigned short ushort_t;
using f32x4  = __attribute__((ext_vector_type(4))) float;
using short8 = __attribute__((ext_vector_type(8))) short;

// ---- bf16 helpers (RNE) ----------------------------------------------------
__device__ __forceinline__ unsigned bfpack(float lo, float hi) {
    union { float f; unsigned u; } a, b; a.f = lo; b.f = hi;
    unsigned ra = (a.u + 0x7fffu + ((a.u >> 16) & 1u)) >> 16;
    unsigned rb = (b.u + 0x7fffu + ((b.u >> 16) & 1u)) & 0xffff0000u;
    return ra | rb;
}

// ---- async global->LDS, 16 B per lane (LDS dest = wave-uniform base) -------
__device__ __forceinline__ void gl_lds16(const void* g, void* l) {
    __builtin_amdgcn_global_load_lds(
        (const __attribute__((address_space(1))) unsigned*)g,
        (__attribute__((address_space(3))) unsigned*)l, 16, 0, 0);
}

// ---------------- phase A: streaming im2col+cast, W swizzle, zeroing --------
// Xp layout: [z][p][i][octet'] where octet' = (o&~7) | ((o&7) ^ (i&7)); each
// octet = 8 bf16 of k = o*8.. (k = c*256+di*16+dj canonical). p-major so a
// (p, 16-image) slab is one contiguous 24 KB region for phase-B DMA.
// Wfrag: [nt(24)][kc(24)][lane(64)][8] bf16 (one frag = one 1 KB segment).
// grid 9408 x 256 = 2408448 threads = 2 * 196 * 64 * 96 octets.
__global__ __launch_bounds__(256) void pe_prep(
    const float* __restrict__ x, const float* __restrict__ y,
    const float* __restrict__ W, ushort_t* __restrict__ Wfrag,
    ushort_t* __restrict__ Xp, float* __restrict__ scal,
    float* __restrict__ Lsum, float* __restrict__ Qsum) {
    const int t = blockIdx.x * 256 + threadIdx.x;
    if (t < 4) scal[t] = 0.f;                   // T, S, pad, done-counter
    if (t < NCOLS / 4) {
        ((float4*)Lsum)[t] = float4{0.f, 0.f, 0.f, 0.f};
        ((float4*)Qsum)[t] = float4{0.f, 0.f, 0.f, 0.f};
    }
    if (t < 36864) {                            // W -> Wfrag swizzle
        const int n  = t / 96;
        const int ko = t % 96;
        const float4 a = *(const float4*)(W + (size_t)n * K_PE + ko * 8);
        const float4 b = *(const float4*)(W + (size_t)n * K_PE + ko * 8 + 4);
        uint4 pk;
        pk.x = bfpack(a.x, a.y); pk.y = bfpack(a.z, a.w);
        pk.z = bfpack(b.x, b.y); pk.w = bfpack(b.z, b.w);
        const int nt   = n >> 4;
        const int kc   = ko >> 2;
        const int lane = (ko & 3) * 16 + (n & 15);
        ((uint4*)Wfrag)[(nt * 24 + kc) * 64 + lane] = pk;
    }
    // ---- patch-matrix build: one octet (8 floats -> 8 bf16) per thread
    const int o = t % 96;
    int rest    = t / 96;
    const int i = rest & 63;
    rest >>= 6;
    const int p = rest % 196;
    const int z = rest / 196;                   // 0 = x, 1 = y
    const int c    = o >> 5;
    const int di   = (o >> 1) & 15;
    const int half = o & 1;
    const int pi   = p / 14;
    const int pj   = p - pi * 14;
    const float* src = (z ? y : x) +
        ((size_t)(i * 3 + c) * 224 + pi * 16 + di) * 224 + pj * 16 + half * 8;
    float4 f0 = *(const float4*)src;
    float4 f1 = *(const float4*)(src + 4);
    uint4 pk;
    pk.x = bfpack(f0.x, f0.y); pk.y = bfpack(f0.z, f0.w);
    pk.z = bfpack(f1.x, f1.y); pk.w = bfpack(f1.z, f1.w);
    const int op = (o & ~7) | ((o & 7) ^ (i & 7));
    ((uint4*)Xp)[(size_t)z * 1204224 + (size_t)(p * 64 + i) * 96 + op] = pk;
}

// ---------------- phase B: GEMM + softmax + partial reduce ------------------
// grid (196, 4): block = (position p, image-quarter ig). Block 256 = 4 waves.
// M = 16 images, N = 384 (4 n-waves x 96), K = 768. A staged via 48
// global_load_lds 1 KB issues (bf16, pre-swizzled by pe_prep, L3-hot),
// ONE barrier, then a barrier-free MFMA K-loop (B-frags direct from
// L2-resident Wfrag, 1 KB coalesced). Epilogue: fused softmax + reduce.
__global__ __launch_bounds__(256, 3) void pe_gemm(
    const ushort_t* __restrict__ Xp, const ushort_t* __restrict__ Wfrag,
    const float* __restrict__ bias, float* __restrict__ scal,
    float* __restrict__ Lsum, float* __restrict__ Qsum) {
    const int p  = blockIdx.x;
    const int ig = blockIdx.y;

    __shared__ __align__(16) ushort_t As[2][16 * 768];   // 48 KB (x, y)
    __shared__ float Smx[4][16], Ssx[4][16], Smy[4][16], Ssy[4][16];
    __shared__ float sT[4];

    const int tid  = threadIdx.x;
    const int wave = tid >> 6;
    const int lane = tid & 63;
    const int lm   = lane & 15;
    const int lq   = lane >> 4;
    const int wn   = wave * 96;

    // ---- A staging: 24 KB per input, 1 KB DMA chunks, 12 issues per wave
    {
        const ushort_t* xs = Xp + (size_t)(p * 64 + ig * 16) * 768;
        const ushort_t* ys = xs + XPHALF;
#pragma unroll
        for (int c6 = 0; c6 < 6; ++c6) {
            const int ch = wave * 6 + c6;           // 0..23
            gl_lds16(xs + (size_t)ch * 512 + lane * 8, &As[0][ch * 512]);
            gl_lds16(ys + (size_t)ch * 512 + lane * 8, &As[1][ch * 512]);
        }
    }

    const ushort_t* bbase = Wfrag + (size_t)lane * 8;
    f32x4 accx[6] = {};
    f32x4 accy[6] = {};

    __syncthreads();   // the ONLY barrier before the epilogue

    // ---- barrier-free K-loop: A from LDS, B from L2 -------------------------
#pragma unroll
    for (int kbi = 0; kbi < 12; ++kbi) {
#pragma unroll
        for (int ks = 0; ks < 2; ++ks) {
            short8 bfr[6];
#pragma unroll
            for (int ni = 0; ni < 6; ++ni)
                bfr[ni] = *(const short8*)(bbase +
                          (size_t)(((wave * 6 + ni) * 24 + kbi * 2 + ks) * 64) * 8);
            const int aoff = lm * 768 +
                             (kbi * 8 + ((ks * 4 + lq) ^ (lm & 7))) * 8;
            short8 afx = *(const short8*)&As[0][aoff];
            short8 afy = *(const short8*)&As[1][aoff];
#pragma unroll
            for (int ni = 0; ni < 6; ++ni) {
                accx[ni] = __builtin_amdgcn_mfma_f32_16x16x32_bf16(
                    afx, bfr[ni], accx[ni], 0, 0, 0);
                accy[ni] = __builtin_amdgcn_mfma_f32_16x16x32_bf16(
                    afy, bfr[ni], accy[ni], 0, 0, 0);
            }
        }
    }

    // ---- epilogue (verified in R8/R9) --------------------------------------
    // D frag: col = wn + ni*16 + lm; row (image in quarter) = lq*4 + r.
#pragma unroll
    for (int ni = 0; ni < 6; ++ni) {
        const float bv = bias[wn + ni * 16 + lm];
#pragma unroll
        for (int r = 0; r < 4; ++r) {
            accx[ni][r] += bv;
            accy[ni][r] += bv;
        }
    }

    float mx[4], my_[4];
#pragma unroll
    for (int r = 0; r < 4; ++r) {
        float a = accx[0][r], b = accy[0][r];
#pragma unroll
        for (int ni = 1; ni < 6; ++ni) {
            a = fmaxf(a, accx[ni][r]);
            b = fmaxf(b, accy[ni][r]);
        }
        mx[r] = a; my_[r] = b;
    }
#pragma unroll
    for (int off = 1; off < 16; off <<= 1)
#pragma unroll
        for (int r = 0; r < 4; ++r) {
            mx[r]  = fmaxf(mx[r],  __shfl_xor(mx[r],  off));
            my_[r] = fmaxf(my_[r], __shfl_xor(my_[r], off));
        }
    if (lm == 0)
#pragma unroll
        for (int r = 0; r < 4; ++r) {
            Smx[wave][lq * 4 + r] = mx[r];
            Smy[wave][lq * 4 + r] = my_[r];
        }
    __syncthreads();
#pragma unroll
    for (int r = 0; r < 4; ++r) {
        const int row = lq * 4 + r;
        mx[r]  = fmaxf(fmaxf(Smx[0][row], Smx[1][row]),
                       fmaxf(Smx[2][row], Smx[3][row]));
        my_[r] = fmaxf(fmaxf(Smy[0][row], Smy[1][row]),
                       fmaxf(Smy[2][row], Smy[3][row]));
    }

    float sx[4], sy[4];
#pragma unroll
    for (int r = 0; r < 4; ++r) {
        float a = 0.f, b = 0.f;
#pragma unroll
        for (int ni = 0; ni < 6; ++ni) {
            a += __expf(accx[ni][r] - mx[r]);
            b += __expf(accy[ni][r] - my_[r]);
        }
        sx[r] = a; sy[r] = b;
    }
#pragma unroll
    for (int off = 1; off < 16; off <<= 1)
#pragma unroll
        for (int r = 0; r < 4; ++r) {
            sx[r] += __shfl_xor(sx[r], off);
            sy[r] += __shfl_xor(sy[r], off);
        }
    if (lm == 0)
#pragma unroll
        for (int r = 0; r < 4; ++r) {
            Ssx[wave][lq * 4 + r] = sx[r];
            Ssy[wave][lq * 4 + r] = sy[r];
        }
    __syncthreads();
#pragma unroll
    for (int r = 0; r < 4; ++r) {
        const int row = lq * 4 + r;
        const float ssx = Ssx[0][row] + Ssx[1][row] + Ssx[2][row] + Ssx[3][row];
        const float ssy = Ssy[0][row] + Ssy[1][row] + Ssy[2][row] + Ssy[3][row];
        sx[r] = mx[r] + __logf(ssx);   // logp shift
        sy[r] = 1.f / ssy;             // q scale
    }

    float T = 0.f;
    float cL[6], cQ[6];
#pragma unroll
    for (int ni = 0; ni < 6; ++ni) { cL[ni] = 0.f; cQ[ni] = 0.f; }
#pragma unroll
    for (int r = 0; r < 4; ++r) {
        const float sh  = sx[r];
        const float m   = my_[r];
        const float inv = sy[r];
#pragma unroll
        for (int ni = 0; ni < 6; ++ni) {
            const float lp = accx[ni][r] - sh;
            const float qv = __expf(accy[ni][r] - m) * inv;
            T += lp * qv;
            cL[ni] += lp;
            cQ[ni] += qv;
        }
    }
#pragma unroll
    for (int ni = 0; ni < 6; ++ni) {
        cL[ni] += __shfl_xor(cL[ni], 16); cL[ni] += __shfl_xor(cL[ni], 32);
        cQ[ni] += __shfl_xor(cQ[ni], 16); cQ[ni] += __shfl_xor(cQ[ni], 32);
    }
    if (lq == 0)
#pragma unroll
        for (int ni = 0; ni < 6; ++ni) {
            const int col = p * HID + wn + ni * 16 + lm;
            atomicAdd(&Lsum[col], cL[ni]);
            atomicAdd(&Qsum[col], cQ[ni]);
        }
#pragma unroll
    for (int off = 32; off > 0; off >>= 1) T += __shfl_xor(T, off);
    if (lane == 0) sT[wave] = T;
    __syncthreads();
    if (tid == 0)
        atomicAdd(&scal[0], sT[0] + sT[1] + sT[2] + sT[3]);
}

// ---------------- S = dot(Lsum,Qsum) + finalize -----------------------------
__global__ __launch_bounds__(256) void final_dot(const float* __restrict__ Lsum,
                                                 const float* __restrict__ Qsum,
                                                 float* __restrict__ scal,
                                                 float* __restrict__ out) {
    const int idx = blockIdx.x * 256 + threadIdx.x;
    float s = 0.f;
    if (idx < NCOLS / 4) {
        float4 a = ((const float4*)Lsum)[idx];
        float4 b = ((const float4*)Qsum)[idx];
        s = a.x * b.x + a.y * b.y + a.z * b.z + a.w * b.w;
    }
#pragma unroll
    for (int off = 32; off > 0; off >>= 1) s += __shfl_xor(s, off);
    __shared__ float sS[4];
    __shared__ int lastflag;
    if ((threadIdx.x & 63) == 0) sS[threadIdx.x >> 6] = s;
    __syncthreads();
    if (threadIdx.x == 0) {
        atomicAdd(&scal[1], sS[0] + sS[1] + sS[2] + sS[3]);
        __threadfence();
        int old = atomicAdd((int*)&scal[3], 1);
        lastflag = (old == (int)gridDim.x - 1);
    }
    __syncthreads();
    if (lastflag && threadIdx.x == 0) {
        float S = atomicAdd(&scal[1], 0.f);   // coherent read-back
        float T = atomicAdd(&scal[0], 0.f);
        out[0] = 63.f * T / (S - T);
    }
}

extern "C" void kernel_launch(void* const* d_in, const int* in_sizes, int n_in,
                              void* d_out, int out_size, void* d_ws, size_t ws_size,
                              hipStream_t stream) {
    const float* x = (const float*)d_in[0];   // (64,3,224,224)
    const float* y = (const float*)d_in[1];   // (64,3,224,224)
    const float* W = (const float*)d_in[2];   // (384,768)
    const float* b = (const float*)d_in[3];   // (384,)
    float* out = (float*)d_out;

    float*    scal  = (float*)d_ws;                   // 16 f32: T,S,pad,cnt
    float*    Lsum  = scal + 16;                      // 75264 f32
    float*    Qsum  = Lsum + NCOLS;                   // 75264 f32
    ushort_t* Wfrag = (ushort_t*)(Qsum + NCOLS);      // 294912 bf16
    ushort_t* Xp    = Wfrag + 294912;                 // 2*9633792 bf16 (38.5 MB)

    pe_prep<<<9408, 256, 0, stream>>>(x, y, W, Wfrag, Xp, scal, Lsum, Qsum);
    pe_gemm<<<dim3(196, 4), 256, 0, stream>>>(Xp, Wfrag, b, scal, Lsum, Qsum);
    final_dot<<<74, 256, 0, stream>>>(Lsum, Qsum, scal, out);
}

// Round 12
// 162.251 us; speedup vs baseline: 1.0142x; 1.0142x over previous
//
#include <hip/hip_runtime.h>

#define HID   384
#define K_PE  768      // 3*16*16
#define IMGST 150528   // 3*224*224 floats per image
#define NCOLS 75264    // 196*384
#define XPHALF 9633792 // ushorts per input in Xp: 196*64*768

typedef unsigned short ushort_t;
using f32x4  = __attribute__((ext_vector_type(4))) float;
using short8 = __attribute__((ext_vector_type(8))) short;
using uint4v = __attribute__((ext_vector_type(4))) unsigned int;

// ---- bf16 helpers (RNE) ----------------------------------------------------
__device__ __forceinline__ unsigned bfpack(float lo, float hi) {
    union { float f; unsigned u; } a, b; a.f = lo; b.f = hi;
    unsigned ra = (a.u + 0x7fffu + ((a.u >> 16) & 1u)) >> 16;
    unsigned rb = (b.u + 0x7fffu + ((b.u >> 16) & 1u)) & 0xffff0000u;
    return ra | rb;
}

// ---- async global->LDS, 16 B per lane, NT cache policy (aux=2 on gfx950) ---
__device__ __forceinline__ void gl_lds16_nt(const void* g, void* l) {
    __builtin_amdgcn_global_load_lds(
        (const __attribute__((address_space(1))) unsigned*)g,
        (__attribute__((address_space(3))) unsigned*)l, 16, 0, 2);
}

// ---------------- phase A: streaming im2col+cast, W swizzle, zeroing --------
// Xp layout: [z][p][i][octet'] where octet' = (o&~7) | ((o&7) ^ (i&7)); each
// octet = 8 bf16 of k = o*8.. (k = c*256+di*16+dj canonical). p-major so a
// (p, 16-image) slab is one contiguous 24 KB region for phase-B DMA.
// Wfrag: [nt(24)][kc(24)][lane(64)][8] bf16 (one frag = one 1 KB segment).
// grid 9408 x 256 = 2408448 threads = 2 * 196 * 64 * 96 octets.
__global__ __launch_bounds__(256) void pe_prep(
    const float* __restrict__ x, const float* __restrict__ y,
    const float* __restrict__ W, ushort_t* __restrict__ Wfrag,
    ushort_t* __restrict__ Xp, float* __restrict__ scal,
    float* __restrict__ Lsum, float* __restrict__ Qsum) {
    const int t = blockIdx.x * 256 + threadIdx.x;
    if (t < 4) scal[t] = 0.f;                   // T, S, pad, done-counter
    if (t < NCOLS / 4) {
        ((float4*)Lsum)[t] = float4{0.f, 0.f, 0.f, 0.f};
        ((float4*)Qsum)[t] = float4{0.f, 0.f, 0.f, 0.f};
    }
    if (t < 36864) {                            // W -> Wfrag swizzle
        const int n  = t / 96;
        const int ko = t % 96;
        const float4 a = *(const float4*)(W + (size_t)n * K_PE + ko * 8);
        const float4 b = *(const float4*)(W + (size_t)n * K_PE + ko * 8 + 4);
        uint4 pk;
        pk.x = bfpack(a.x, a.y); pk.y = bfpack(a.z, a.w);
        pk.z = bfpack(b.x, b.y); pk.w = bfpack(b.z, b.w);
        const int nt   = n >> 4;
        const int kc   = ko >> 2;
        const int lane = (ko & 3) * 16 + (n & 15);
        ((uint4*)Wfrag)[(nt * 24 + kc) * 64 + lane] = pk;
    }
    // ---- patch-matrix build: one octet (8 floats -> 8 bf16) per thread
    const int o = t % 96;
    int rest    = t / 96;
    const int i = rest & 63;
    rest >>= 6;
    const int p = rest % 196;
    const int z = rest / 196;                   // 0 = x, 1 = y
    const int c    = o >> 5;
    const int di   = (o >> 1) & 15;
    const int half = o & 1;
    const int pi   = p / 14;
    const int pj   = p - pi * 14;
    const float* src = (z ? y : x) +
        ((size_t)(i * 3 + c) * 224 + pi * 16 + di) * 224 + pj * 16 + half * 8;
    float4 f0 = *(const float4*)src;
    float4 f1 = *(const float4*)(src + 4);
    uint4v pk;
    pk.x = bfpack(f0.x, f0.y); pk.y = bfpack(f0.z, f0.w);
    pk.z = bfpack(f1.x, f1.y); pk.w = bfpack(f1.z, f1.w);
    const int op = (o & ~7) | ((o & 7) ^ (i & 7));
    __builtin_nontemporal_store(pk,
        (uint4v*)Xp + (size_t)z * 1204224 + (size_t)(p * 64 + i) * 96 + op);
}

// ---------------- phase B: GEMM + softmax + partial reduce ------------------
// grid (196, 4): block = (position p, image-quarter ig). Block 256 = 4 waves.
// M = 16 images, N = 384 (4 n-waves x 96), K = 768. A staged via 24 NT
// global_load_lds 1 KB issues (evict-first: keeps Wfrag L2-resident), ONE
// barrier, then a barrier-free MFMA K-loop with explicit one-step register
// prefetch of B-frags (L2) and A-frags (LDS). Epilogue: softmax + reduce.
__global__ __launch_bounds__(256, 3) void pe_gemm(
    const ushort_t* __restrict__ Xp, const ushort_t* __restrict__ Wfrag,
    const float* __restrict__ bias, float* __restrict__ scal,
    float* __restrict__ Lsum, float* __restrict__ Qsum) {
    const int p  = blockIdx.x;
    const int ig = blockIdx.y;

    __shared__ __align__(16) ushort_t As[2][16 * 768];   // 48 KB (x, y)
    __shared__ float Smx[4][16], Ssx[4][16], Smy[4][16], Ssy[4][16];
    __shared__ float sT[4];

    const int tid  = threadIdx.x;
    const int wave = tid >> 6;
    const int lane = tid & 63;
    const int lm   = lane & 15;
    const int lq   = lane >> 4;
    const int wn   = wave * 96;

    // ---- A staging DMA (NT): 24 KB per input, 1 KB chunks, 12 issues/wave
    {
        const ushort_t* xs = Xp + (size_t)(p * 64 + ig * 16) * 768;
        const ushort_t* ys = xs + XPHALF;
#pragma unroll
        for (int c6 = 0; c6 < 6; ++c6) {
            const int ch = wave * 6 + c6;           // 0..23
            gl_lds16_nt(xs + (size_t)ch * 512 + lane * 8, &As[0][ch * 512]);
            gl_lds16_nt(ys + (size_t)ch * 512 + lane * 8, &As[1][ch * 512]);
        }
    }

    const ushort_t* bbase = Wfrag + (size_t)lane * 8;
#define BPTR(STEP, NI) ((const short8*)(bbase + \
        (size_t)(((wave * 6 + (NI)) * 24 + (STEP)) * 64) * 8))
#define AOFF(STEP) (lm * 768 + (((STEP) >> 1) * 8 + \
        (((((STEP) & 1) * 4) + lq) ^ (lm & 7))) * 8)

    f32x4 accx[6] = {};
    f32x4 accy[6] = {};

    // B-frags for step 0 issued BEFORE the barrier (overlap the A DMA)
    short8 bcur[6], bnxt[6];
#pragma unroll
    for (int ni = 0; ni < 6; ++ni) bcur[ni] = *BPTR(0, ni);

    __syncthreads();   // the ONLY barrier before the epilogue

    short8 axc = *(const short8*)&As[0][AOFF(0)];
    short8 ayc = *(const short8*)&As[1][AOFF(0)];

    // ---- K-loop: 24 steps, one-step-ahead register prefetch ----------------
#pragma unroll
    for (int step = 0; step < 24; ++step) {
        short8 axn, ayn;
        if (step < 23) {
#pragma unroll
            for (int ni = 0; ni < 6; ++ni) bnxt[ni] = *BPTR(step + 1, ni);
            axn = *(const short8*)&As[0][AOFF(step + 1)];
            ayn = *(const short8*)&As[1][AOFF(step + 1)];
        }
#pragma unroll
        for (int ni = 0; ni < 6; ++ni) {
            accx[ni] = __builtin_amdgcn_mfma_f32_16x16x32_bf16(
                axc, bcur[ni], accx[ni], 0, 0, 0);
            accy[ni] = __builtin_amdgcn_mfma_f32_16x16x32_bf16(
                ayc, bcur[ni], accy[ni], 0, 0, 0);
        }
        if (step < 23) {
#pragma unroll
            for (int ni = 0; ni < 6; ++ni) bcur[ni] = bnxt[ni];
            axc = axn; ayc = ayn;
        }
    }
#undef BPTR
#undef AOFF

    // ---- epilogue (verified in R8-R10) -------------------------------------
    // D frag: col = wn + ni*16 + lm; row (image in quarter) = lq*4 + r.
#pragma unroll
    for (int ni = 0; ni < 6; ++ni) {
        const float bv = bias[wn + ni * 16 + lm];
#pragma unroll
        for (int r = 0; r < 4; ++r) {
            accx[ni][r] += bv;
            accy[ni][r] += bv;
        }
    }

    float mx[4], my_[4];
#pragma unroll
    for (int r = 0; r < 4; ++r) {
        float a = accx[0][r], b = accy[0][r];
#pragma unroll
        for (int ni = 1; ni < 6; ++ni) {
            a = fmaxf(a, accx[ni][r]);
            b = fmaxf(b, accy[ni][r]);
        }
        mx[r] = a; my_[r] = b;
    }
#pragma unroll
    for (int off = 1; off < 16; off <<= 1)
#pragma unroll
        for (int r = 0; r < 4; ++r) {
            mx[r]  = fmaxf(mx[r],  __shfl_xor(mx[r],  off));
            my_[r] = fmaxf(my_[r], __shfl_xor(my_[r], off));
        }
    if (lm == 0)
#pragma unroll
        for (int r = 0; r < 4; ++r) {
            Smx[wave][lq * 4 + r] = mx[r];
            Smy[wave][lq * 4 + r] = my_[r];
        }
    __syncthreads();
#pragma unroll
    for (int r = 0; r < 4; ++r) {
        const int row = lq * 4 + r;
        mx[r]  = fmaxf(fmaxf(Smx[0][row], Smx[1][row]),
                       fmaxf(Smx[2][row], Smx[3][row]));
        my_[r] = fmaxf(fmaxf(Smy[0][row], Smy[1][row]),
                       fmaxf(Smy[2][row], Smy[3][row]));
    }

    float sx[4], sy[4];
#pragma unroll
    for (int r = 0; r < 4; ++r) {
        float a = 0.f, b = 0.f;
#pragma unroll
        for (int ni = 0; ni < 6; ++ni) {
            a += __expf(accx[ni][r] - mx[r]);
            b += __expf(accy[ni][r] - my_[r]);
        }
        sx[r] = a; sy[r] = b;
    }
#pragma unroll
    for (int off = 1; off < 16; off <<= 1)
#pragma unroll
        for (int r = 0; r < 4; ++r) {
            sx[r] += __shfl_xor(sx[r], off);
            sy[r] += __shfl_xor(sy[r], off);
        }
    if (lm == 0)
#pragma unroll
        for (int r = 0; r < 4; ++r) {
            Ssx[wave][lq * 4 + r] = sx[r];
            Ssy[wave][lq * 4 + r] = sy[r];
        }
    __syncthreads();
#pragma unroll
    for (int r = 0; r < 4; ++r) {
        const int row = lq * 4 + r;
        const float ssx = Ssx[0][row] + Ssx[1][row] + Ssx[2][row] + Ssx[3][row];
        const float ssy = Ssy[0][row] + Ssy[1][row] + Ssy[2][row] + Ssy[3][row];
        sx[r] = mx[r] + __logf(ssx);   // logp shift
        sy[r] = 1.f / ssy;             // q scale
    }

    float T = 0.f;
    float cL[6], cQ[6];
#pragma unroll
    for (int ni = 0; ni < 6; ++ni) { cL[ni] = 0.f; cQ[ni] = 0.f; }
#pragma unroll
    for (int r = 0; r < 4; ++r) {
        const float sh  = sx[r];
        const float m   = my_[r];
        const float inv = sy[r];
#pragma unroll
        for (int ni = 0; ni < 6; ++ni) {
            const float lp = accx[ni][r] - sh;
            const float qv = __expf(accy[ni][r] - m) * inv;
            T += lp * qv;
            cL[ni] += lp;
            cQ[ni] += qv;
        }
    }
#pragma unroll
    for (int ni = 0; ni < 6; ++ni) {
        cL[ni] += __shfl_xor(cL[ni], 16); cL[ni] += __shfl_xor(cL[ni], 32);
        cQ[ni] += __shfl_xor(cQ[ni], 16); cQ[ni] += __shfl_xor(cQ[ni], 32);
    }
    if (lq == 0)
#pragma unroll
        for (int ni = 0; ni < 6; ++ni) {
            const int col = p * HID + wn + ni * 16 + lm;
            atomicAdd(&Lsum[col], cL[ni]);
            atomicAdd(&Qsum[col], cQ[ni]);
        }
#pragma unroll
    for (int off = 32; off > 0; off >>= 1) T += __shfl_xor(T, off);
    if (lane == 0) sT[wave] = T;
    __syncthreads();
    if (tid == 0)
        atomicAdd(&scal[0], sT[0] + sT[1] + sT[2] + sT[3]);
}

// ---------------- S = dot(Lsum,Qsum) + finalize -----------------------------
__global__ __launch_bounds__(256) void final_dot(const float* __restrict__ Lsum,
                                                 const float* __restrict__ Qsum,
                                                 float* __restrict__ scal,
                                                 float* __restrict__ out) {
    const int idx = blockIdx.x * 256 + threadIdx.x;
    float s = 0.f;
    if (idx < NCOLS / 4) {
        float4 a = ((const float4*)Lsum)[idx];
        float4 b = ((const float4*)Qsum)[idx];
        s = a.x * b.x + a.y * b.y + a.z * b.z + a.w * b.w;
    }
#pragma unroll
    for (int off = 32; off > 0; off >>= 1) s += __shfl_xor(s, off);
    __shared__ float sS[4];
    __shared__ int lastflag;
    if ((threadIdx.x & 63) == 0) sS[threadIdx.x >> 6] = s;
    __syncthreads();
    if (threadIdx.x == 0) {
        atomicAdd(&scal[1], sS[0] + sS[1] + sS[2] + sS[3]);
        __threadfence();
        int old = atomicAdd((int*)&scal[3], 1);
        lastflag = (old == (int)gridDim.x - 1);
    }
    __syncthreads();
    if (lastflag && threadIdx.x == 0) {
        float S = atomicAdd(&scal[1], 0.f);   // coherent read-back
        float T = atomicAdd(&scal[0], 0.f);
        out[0] = 63.f * T / (S - T);
    }
}

extern "C" void kernel_launch(void* const* d_in, const int* in_sizes, int n_in,
                              void* d_out, int out_size, void* d_ws, size_t ws_size,
                              hipStream_t stream) {
    const float* x = (const float*)d_in[0];   // (64,3,224,224)
    const float* y = (const float*)d_in[1];   // (64,3,224,224)
    const float* W = (const float*)d_in[2];   // (384,768)
    const float* b = (const float*)d_in[3];   // (384,)
    float* out = (float*)d_out;

    float*    scal  = (float*)d_ws;                   // 16 f32: T,S,pad,cnt
    float*    Lsum  = scal + 16;                      // 75264 f32
    float*    Qsum  = Lsum + NCOLS;                   // 75264 f32
    ushort_t* Wfrag = (ushort_t*)(Qsum + NCOLS);      // 294912 bf16
    ushort_t* Xp    = Wfrag + 294912;                 // 2*9633792 bf16 (38.5 MB)

    pe_prep<<<9408, 256, 0, stream>>>(x, y, W, Wfrag, Xp, scal, Lsum, Qsum);
    pe_gemm<<<dim3(196, 4), 256, 0, stream>>>(Xp, Wfrag, b, scal, Lsum, Qsum);
    final_dot<<<74, 256, 0, stream>>>(Lsum, Qsum, scal, out);
}